// Round 7
// baseline (466.140 us; speedup 1.0000x reference)
//
#include <hip/hip_runtime.h>

#define NN 20000
#define EE 320000
#define BB 64

typedef _Float16 half8 __attribute__((ext_vector_type(8)));
typedef float floatx4 __attribute__((ext_vector_type(4)));

// ---------------- prep: weight folding ----------------
__global__ void k_prep_edgeW(const float* __restrict__ edge_W, const float* __restrict__ edge_b,
                             const float* __restrict__ We0, const float* __restrict__ We1,
                             _Float16* __restrict__ Wpt0, _Float16* __restrict__ Wpt1) {
    __shared__ float row[256];
    int k = blockIdx.x, layer = blockIdx.y, j = threadIdx.x;
    row[j] = (k < 63) ? edge_W[k*256 + j] : edge_b[j];
    __syncthreads();
    const float* We = layer ? We1 : We0;
    float acc = 0.f;
    for (int t = 0; t < 256; ++t) acc += row[t] * We[t*256 + j];
    (layer ? Wpt1 : Wpt0)[j*64 + k] = (_Float16)acc;   // transposed [col][k] fp16
}

__global__ void k_prep_acat(const float* __restrict__ node_W, const float* __restrict__ node_b,
                            const float* __restrict__ Wl0, const float* __restrict__ bl0,
                            const float* __restrict__ Wr0, const float* __restrict__ br0,
                            float* __restrict__ Acat) {
    __shared__ float row[256];
    int k = blockIdx.x, j = threadIdx.x;
    if (j < 256) row[j] = (k < 5) ? node_W[k*256 + j] : node_b[j];
    __syncthreads();
    int jj = j & 255;
    const float* W = (j < 256) ? Wl0 : Wr0;
    float acc = 0.f;
    for (int t = 0; t < 256; ++t) acc += row[t] * W[t*256 + jj];
    if (k == 5) acc += (j < 256) ? bl0[jj] : br0[jj];
    Acat[k*512 + j] = acc;
}

__global__ void k_prep_t16(const float* __restrict__ Wl1, const float* __restrict__ bl1,
                           const float* __restrict__ Wr1, const float* __restrict__ br1,
                           const float* __restrict__ mlp_W,
                           _Float16* __restrict__ WlWr1t, float* __restrict__ blr1,
                           _Float16* __restrict__ mlpWt) {
    int n = blockIdx.x, k = threadIdx.x;
    if (n < 512) {
        float v = (n < 256) ? Wl1[k*256 + n] : Wr1[k*256 + (n - 256)];
        WlWr1t[n*256 + k] = (_Float16)v;
        if (k == 0) blr1[n] = (n < 256) ? bl1[n] : br1[n - 256];
    } else {
        int nn = n - 512;
        mlpWt[nn*256 + k] = (_Float16)mlp_W[k*64 + nn];
    }
}

// ---------------- CSR by dst ----------------
__global__ void k_hist(const int* __restrict__ ei, int* __restrict__ counts) {
    int e = blockIdx.x*256 + threadIdx.x;
    if (e < EE) atomicAdd(&counts[ei[EE + e]], 1);
}

__global__ __launch_bounds__(1024) void k_scan(const int* __restrict__ counts,
                                               int* __restrict__ row_ptr, int* __restrict__ cursor) {
    __shared__ int part[1024];
    int t = threadIdx.x;
    const int per = (NN + 1023) / 1024;
    int b0 = t*per, b1 = min(b0 + per, NN);
    int s = 0;
    for (int i = b0; i < b1; ++i) s += counts[i];
    part[t] = s; __syncthreads();
    for (int d = 1; d < 1024; d <<= 1) {
        int v = (t >= d) ? part[t-d] : 0;
        __syncthreads();
        part[t] += v;
        __syncthreads();
    }
    int run = (t == 0) ? 0 : part[t-1];
    for (int i = b0; i < b1; ++i) { row_ptr[i] = run; cursor[i] = run; run += counts[i]; }
    if (t == 0) row_ptr[NN] = EE;
}

__global__ void k_scatter(const int* __restrict__ ei, int* __restrict__ cursor,
                          int* __restrict__ pos, int* __restrict__ csr_src) {
    int e = blockIdx.x*256 + threadIdx.x;
    if (e < EE) {
        int d = ei[EE + e];
        int p = atomicAdd(&cursor[d], 1);
        pos[e] = p;
        csr_src[p] = ei[e];
    }
}

// permute attr into CSR order, fp32->fp16, 64-wide with bias lane (k=63 -> 1.0)
__global__ void k_permattr(const float* __restrict__ attr, const int* __restrict__ pos,
                           _Float16* __restrict__ attr16) {
    int tid = threadIdx.x;
    int w = tid >> 6, lane = tid & 63;
    int e = blockIdx.x*4 + w;
    if (e >= EE) return;
    float v = (lane < 63) ? attr[(size_t)e*63 + lane] : 1.0f;
    attr16[(size_t)pos[e]*64 + lane] = (_Float16)v;
}

// ---------------- layer 0 xl/xr via folded K=5 (fp16 out) ----------------
__global__ void k_xlxr0(const float* __restrict__ x, const float* __restrict__ Acat,
                        _Float16* __restrict__ xlxr16) {
    int n = blockIdx.x, j = threadIdx.x;
    float a0 = Acat[5*512 + j], a1 = Acat[5*512 + 256 + j];
#pragma unroll
    for (int k = 0; k < 5; ++k) {
        float xv = x[n*5 + k];
        a0 += xv * Acat[k*512 + j];
        a1 += xv * Acat[k*512 + 256 + j];
    }
    xlxr16[(size_t)n*512 + j] = (_Float16)a0;
    xlxr16[(size_t)n*512 + 256 + j] = (_Float16)a1;
}

// ---------------- fused GATv2 layer, barrier-free wave-private pipeline ----------------
// 4 waves/block; wave w = head w. Each wave: private double-buffered LDS xl-slice
// (16 rows x 64 cols of its head), cross-node tile prefetch over contiguous CSR.
// GAT bias dropped (cancels exactly in training-mode BN). Output fp16.
#define NPB 4
__global__ __launch_bounds__(256) void k_fused(const _Float16* __restrict__ attr16,
        const int* __restrict__ csrc, const int* __restrict__ row_ptr,
        const _Float16* __restrict__ Wpt, const float* __restrict__ att,
        const _Float16* __restrict__ xlxr16, _Float16* __restrict__ gat16) {
    int tid = threadIdx.x;
    int wave = tid >> 6, lane = tid & 63;
    int l15 = lane & 15, l4 = lane >> 4;

    __shared__ __align__(16) _Float16 xls[4][2][16][72];   // wave-private [buf][row][col(+pad)]

    // block-invariant: B fragments (Wpt) + att for this wave's head
    half8 bf[4][2];
    float attv[4];
#pragma unroll
    for (int ct = 0; ct < 4; ++ct) {
        int c = wave*64 + ct*16 + l15;
        attv[ct] = att[c];
        bf[ct][0] = *(const half8*)&Wpt[(size_t)c*64 + l4*8];
        bf[ct][1] = *(const half8*)&Wpt[(size_t)c*64 + 32 + l4*8];
    }

    int n = blockIdx.x*NPB;
    int nEnd = n + NPB; if (nEnd > NN) nEnd = NN;
    int s_n = row_ptr[n];
    int e_n;
    // advance to first nonempty node (emit zeros for empties)
    for (;;) {
        if (n >= nEnd) return;
        e_n = row_ptr[n+1];
        if (e_n > s_n) break;
        gat16[(size_t)n*256 + wave*64 + lane] = (_Float16)0.f;
        ++n; s_n = e_n;
    }
    const int E = row_ptr[nEnd];
    int t0 = s_n;

    // staging regs: rx = xl tile, ra/rb = attr fragments (cur/next)
    half8 rx0, rx1, ra0, ra1, rb0, rb1;
    int srow = lane >> 2, scol = (lane & 3) * 16;

    // prologue: tile t0
    {
        int er = t0 + srow; if (er >= EE) er = EE - 1;
        const _Float16* sp = &xlxr16[(size_t)csrc[er]*512 + wave*64 + scol];
        rx0 = *(const half8*)&sp[0];
        rx1 = *(const half8*)&sp[8];
        int arow = t0 + l15; if (arow >= EE) arow = EE - 1;
        const _Float16* ap = &attr16[(size_t)arow*64];
        ra0 = *(const half8*)&ap[l4*8];
        ra1 = *(const half8*)&ap[32 + l4*8];
    }
    *(half8*)&xls[wave][0][srow][scol]     = rx0;
    *(half8*)&xls[wave][0][srow][scol + 8] = rx1;
    int tn = (t0 + 16 < e_n) ? t0 + 16 : e_n;
    bool hasNext = tn < E;
    if (hasNext) {
        int er = tn + srow; if (er >= EE) er = EE - 1;
        const _Float16* sp = &xlxr16[(size_t)csrc[er]*512 + wave*64 + scol];
        rx0 = *(const half8*)&sp[0];
        rx1 = *(const half8*)&sp[8];
        int arow = tn + l15; if (arow >= EE) arow = EE - 1;
        const _Float16* ap = &attr16[(size_t)arow*64];
        rb0 = *(const half8*)&ap[l4*8];
        rb1 = *(const half8*)&ap[32 + l4*8];
    }

    // per-node xr fragment
    float xrf[4];
#pragma unroll
    for (int ct = 0; ct < 4; ++ct)
        xrf[ct] = (float)xlxr16[(size_t)n*512 + 256 + wave*64 + ct*16 + l15];

    float m_run = -3.0e38f, l_run = 0.f, out_acc = 0.f;
    int cur = 0;
    for (;;) {
        int nt = e_n - t0; if (nt > 16) nt = 16;
        // ---- compute tile [t0, t0+nt) on buf cur ----
        floatx4 acc[4];
#pragma unroll
        for (int ct = 0; ct < 4; ++ct) {
            floatx4 z = {};
            acc[ct] = __builtin_amdgcn_mfma_f32_16x16x32_f16(ra0, bf[ct][0], z, 0, 0, 0);
            acc[ct] = __builtin_amdgcn_mfma_f32_16x16x32_f16(ra1, bf[ct][1], acc[ct], 0, 0, 0);
        }
        float p[4];
#pragma unroll
        for (int r = 0; r < 4; ++r) {
            int eidx = l4*4 + r;
            float pv = 0.f;
#pragma unroll
            for (int ct = 0; ct < 4; ++ct) {
                float m = acc[ct][r] + (float)xls[wave][cur][eidx][ct*16 + l15] + xrf[ct];
                float lr = (m > 0.f) ? m : 0.2f*m;
                pv += lr * attv[ct];
            }
            pv += __shfl_xor(pv, 1);
            pv += __shfl_xor(pv, 2);
            pv += __shfl_xor(pv, 4);
            pv += __shfl_xor(pv, 8);
            p[r] = (eidx < nt) ? pv : -3.0e38f;
        }
        float aall[16];
#pragma unroll
        for (int k = 0; k < 16; ++k)
            aall[k] = __shfl(p[k & 3], (k >> 2) << 4);
        float mt = aall[0];
#pragma unroll
        for (int k = 1; k < 16; ++k) mt = fmaxf(mt, aall[k]);
        float mnew = fmaxf(m_run, mt);
        float scale = __expf(m_run - mnew);
        out_acc *= scale; l_run *= scale;
#pragma unroll
        for (int k = 0; k < 16; ++k) {
            float wk = __expf(aall[k] - mnew);
            l_run += wk;
            out_acc += wk * (float)xls[wave][cur][k][lane];
        }
        m_run = mnew;
        // ---- node end? ----
        if (t0 + 16 >= e_n) {
            gat16[(size_t)n*256 + wave*64 + lane] = (_Float16)(out_acc / l_run);
            ++n; s_n = e_n;
            for (;;) {
                if (n >= nEnd) return;
                e_n = row_ptr[n+1];
                if (e_n > s_n) break;
                gat16[(size_t)n*256 + wave*64 + lane] = (_Float16)0.f;
                ++n; s_n = e_n;
            }
            m_run = -3.0e38f; l_run = 0.f; out_acc = 0.f;
#pragma unroll
            for (int ct = 0; ct < 4; ++ct)
                xrf[ct] = (float)xlxr16[(size_t)n*512 + 256 + wave*64 + ct*16 + l15];
        }
        // advance pipeline: t0 <- tn (== new node start or t0+16)
        t0 = tn;
        *(half8*)&xls[wave][cur^1][srow][scol]     = rx0;
        *(half8*)&xls[wave][cur^1][srow][scol + 8] = rx1;
        ra0 = rb0; ra1 = rb1;
        tn = (t0 + 16 < e_n) ? t0 + 16 : e_n;
        hasNext = tn < E;
        if (hasNext) {
            int er = tn + srow; if (er >= EE) er = EE - 1;
            const _Float16* sp = &xlxr16[(size_t)csrc[er]*512 + wave*64 + scol];
            rx0 = *(const half8*)&sp[0];
            rx1 = *(const half8*)&sp[8];
            int arow = tn + l15; if (arow >= EE) arow = EE - 1;
            const _Float16* ap = &attr16[(size_t)arow*64];
            rb0 = *(const half8*)&ap[l4*8];
            rb1 = *(const half8*)&ap[32 + l4*8];
        }
        cur ^= 1;
    }
}

// ---------------- batchnorm (stats from fp16, apply fused into GEMM) ----------------
__global__ void k_bn_stats(const _Float16* __restrict__ X, float* __restrict__ stats) {
    int j = threadIdx.x;
    int shard = blockIdx.x & 15;
    float s = 0.f, q = 0.f;
    for (int r = blockIdx.x; r < NN; r += gridDim.x) {
        float v = (float)X[(size_t)r*256 + j];
        s += v; q += v*v;
    }
    atomicAdd(&stats[shard*512 + j], s);
    atomicAdd(&stats[shard*512 + 256 + j], q);
}

__global__ void k_bn_final(const float* __restrict__ stats, const float* __restrict__ gamma,
                           const float* __restrict__ beta, float* __restrict__ ss) {
    int j = threadIdx.x;
    float s = 0.f, q = 0.f;
#pragma unroll
    for (int sh = 0; sh < 16; ++sh) {
        s += stats[sh*512 + j];
        q += stats[sh*512 + 256 + j];
    }
    float mean = s * (1.0f/NN);
    float var  = q * (1.0f/NN) - mean*mean;
    float sc = rsqrtf(var + 1e-5f) * gamma[j];
    ss[j] = sc;
    ss[256 + j] = beta[j] - mean*sc;
}

// ---------------- fp16 MFMA GEMM with fused BN+ReLU on A ----------------
// C[M,cols] = relu(bn(A)) @ Bt^T + bias ; A = gat16 [M][256], bn via ss (sc, sh)
template<bool RELU, typename OT>
__global__ __launch_bounds__(256) void k_gemm(const _Float16* __restrict__ A,
                       const float* __restrict__ ssv,
                       const _Float16* __restrict__ Bt,
                       const float* __restrict__ bias, OT* __restrict__ C,
                       int M, int ldc) {
    __shared__ __align__(16) _Float16 As[128][72];
    __shared__ __align__(16) _Float16 Bs[64][72];
    int tid = threadIdx.x;
    int wave = tid >> 6, lane = tid & 63;
    int l15 = lane & 15, l4 = lane >> 4;
    int row0 = blockIdx.x*128, n0 = blockIdx.y*64;
    floatx4 acc[2][4] = {};
    for (int k0 = 0; k0 < 256; k0 += 64) {
#pragma unroll
        for (int q = 0; q < 4; ++q) {
            int c = tid + q*256;
            int r = c >> 3, kc = (c & 7)*8;
            int gr = row0 + r; if (gr >= M) gr = M - 1;
            half8 g = *(const half8*)&A[(size_t)gr*256 + k0 + kc];
            _Float16 tmp[8];
#pragma unroll
            for (int i = 0; i < 8; ++i) {
                int colk = k0 + kc + i;
                float v = (float)g[i]*ssv[colk] + ssv[256 + colk];
                tmp[i] = (_Float16)fmaxf(v, 0.f);
            }
            *(half8*)&As[r][kc] = *(half8*)tmp;
        }
#pragma unroll
        for (int q = 0; q < 2; ++q) {
            int c = tid + q*256;
            int r = c >> 3, kc = (c & 7)*8;
            *(half8*)&Bs[r][kc] = *(const half8*)&Bt[(size_t)(n0 + r)*256 + k0 + kc];
        }
        __syncthreads();
#pragma unroll
        for (int ks = 0; ks < 64; ks += 32) {
            half8 a0 = *(const half8*)&As[wave*32 + l15][ks + l4*8];
            half8 a1 = *(const half8*)&As[wave*32 + 16 + l15][ks + l4*8];
#pragma unroll
            for (int nb = 0; nb < 4; ++nb) {
                half8 b = *(const half8*)&Bs[nb*16 + l15][ks + l4*8];
                acc[0][nb] = __builtin_amdgcn_mfma_f32_16x16x32_f16(a0, b, acc[0][nb], 0, 0, 0);
                acc[1][nb] = __builtin_amdgcn_mfma_f32_16x16x32_f16(a1, b, acc[1][nb], 0, 0, 0);
            }
        }
        __syncthreads();
    }
#pragma unroll
    for (int m = 0; m < 2; ++m)
#pragma unroll
    for (int nb = 0; nb < 4; ++nb) {
        int col = n0 + nb*16 + l15;
        float bv = bias[col];
#pragma unroll
        for (int r = 0; r < 4; ++r) {
            int grow = row0 + wave*32 + m*16 + l4*4 + r;
            if (grow < M) {
                float v = acc[m][nb][r] + bv;
                if (RELU) v = fmaxf(v, 0.f);
                C[(size_t)grow*ldc + col] = (OT)v;
            }
        }
    }
}

// ---------------- pooling (batch sorted -> contiguous ranges, no atomics) ----------------
__global__ void k_pool2(const float* __restrict__ mo, const int* __restrict__ batch,
                        float* __restrict__ pooledDiv) {
    int b = blockIdx.x;
    int j = threadIdx.x & 63, rg = threadIdx.x >> 6;
    int lo = 0, hi = NN;
    while (lo < hi) { int mid = (lo + hi) >> 1; if (batch[mid] < b) lo = mid + 1; else hi = mid; }
    int s = lo;
    lo = 0; hi = NN;
    while (lo < hi) { int mid = (lo + hi) >> 1; if (batch[mid] < b + 1) lo = mid + 1; else hi = mid; }
    int e = lo;
    float acc = 0.f;
    for (int r = s + rg; r < e; r += 4) acc += mo[(size_t)r*64 + j];
    __shared__ float red[256];
    red[threadIdx.x] = acc;
    __syncthreads();
    if (rg == 0) {
        float v = red[j] + red[64 + j] + red[128 + j] + red[192 + j];
        pooledDiv[b*64 + j] = v / fmaxf((float)(e - s), 1.f);
    }
}

__global__ void k_final(const float* __restrict__ pooledDiv,
                        const float* __restrict__ outW, const float* __restrict__ outb,
                        float* __restrict__ out) {
    int t = threadIdx.x;
    if (t >= 320) return;
    int b = t / 5, c = t % 5;
    float acc = outb[c];
    for (int k = 0; k < 64; ++k) acc += pooledDiv[b*64 + k] * outW[k*5 + c];
    out[t] = acc;
}

extern "C" void kernel_launch(void* const* d_in, const int* in_sizes, int n_in,
                              void* d_out, int out_size, void* d_ws, size_t ws_size,
                              hipStream_t stream) {
    const float* x      = (const float*)d_in[0];
    const int*   ei     = (const int*)d_in[1];
    const float* attr   = (const float*)d_in[2];
    const int*   batch  = (const int*)d_in[3];
    const float* node_W = (const float*)d_in[4];
    const float* node_b = (const float*)d_in[5];
    const float* edge_W = (const float*)d_in[6];
    const float* edge_b = (const float*)d_in[7];
    const float* Wl[2]   = {(const float*)d_in[8],  (const float*)d_in[17]};
    const float* bl[2]   = {(const float*)d_in[9],  (const float*)d_in[18]};
    const float* Wr[2]   = {(const float*)d_in[10], (const float*)d_in[19]};
    const float* br[2]   = {(const float*)d_in[11], (const float*)d_in[20]};
    const float* We[2]   = {(const float*)d_in[12], (const float*)d_in[21]};
    const float* att[2]  = {(const float*)d_in[13], (const float*)d_in[22]};
    const float* gamma[2]= {(const float*)d_in[15], (const float*)d_in[24]};
    const float* beta[2] = {(const float*)d_in[16], (const float*)d_in[25]};
    const float* mlp_W = (const float*)d_in[26];
    const float* mlp_b = (const float*)d_in[27];
    const float* out_W = (const float*)d_in[28];
    const float* out_b = (const float*)d_in[29];
    float* out = (float*)d_out;

    char* p = (char*)d_ws;
    size_t off = 0;
    auto carve = [&](size_t bytes) -> void* {
        void* r = p + off;
        off = (off + bytes + 255) & ~(size_t)255;
        return r;
    };
    _Float16* Wpt0   = (_Float16*)carve(256*64*2);
    _Float16* Wpt1   = (_Float16*)carve(256*64*2);
    float*    Acat   = (float*)carve(6*512*4);
    _Float16* WlWr1t = (_Float16*)carve(512*256*2);
    float*    blr1   = (float*)carve(512*4);
    _Float16* mlpWt  = (_Float16*)carve(64*256*2);
    float*    ss     = (float*)carve(512*4);
    _Float16* xlxr16 = (_Float16*)carve((size_t)NN*512*2);
    _Float16* gat16  = (_Float16*)carve((size_t)NN*256*2);
    float*    mlo    = (float*)carve((size_t)NN*64*4);
    _Float16* attr16 = (_Float16*)carve((size_t)EE*64*2);
    int*      row_ptr= (int*)carve((NN+1)*4);
    int*      pos    = (int*)carve((size_t)EE*4);
    int*      csrc   = (int*)carve((size_t)EE*4);
    int*      cursor = (int*)carve(NN*4);
    float*    pooledDiv = (float*)carve(BB*64*4);
    char*     zz     = (char*)carve((NN + 16384)*4);
    int*      counts = (int*)zz;
    float*    stats  = (float*)(zz + (size_t)NN*4);   // 2 layers x 16 shards x 512
    if (off > ws_size) return;  // workspace too small: bail

    hipMemsetAsync(zz, 0, (size_t)(NN + 16384)*4, stream);
    k_prep_edgeW<<<dim3(64,2), 256, 0, stream>>>(edge_W, edge_b, We[0], We[1], Wpt0, Wpt1);
    k_prep_acat<<<6, 512, 0, stream>>>(node_W, node_b, Wl[0], bl[0], Wr[0], br[0], Acat);
    k_prep_t16<<<576, 256, 0, stream>>>(Wl[1], bl[1], Wr[1], br[1], mlp_W, WlWr1t, blr1, mlpWt);
    k_hist<<<(EE+255)/256, 256, 0, stream>>>(ei, counts);
    k_scan<<<1, 1024, 0, stream>>>(counts, row_ptr, cursor);
    k_scatter<<<(EE+255)/256, 256, 0, stream>>>(ei, cursor, pos, csrc);
    k_permattr<<<EE/4, 256, 0, stream>>>(attr, pos, attr16);
    k_xlxr0<<<NN, 256, 0, stream>>>(x, Acat, xlxr16);

    for (int L = 0; L < 2; ++L) {
        k_fused<<<(NN + NPB - 1)/NPB, 256, 0, stream>>>(attr16, csrc, row_ptr,
                 L ? Wpt1 : Wpt0, att[L], xlxr16, gat16);
        k_bn_stats<<<1024, 256, 0, stream>>>(gat16, stats + L*8192);
        k_bn_final<<<1, 256, 0, stream>>>(stats + L*8192, gamma[L], beta[L], ss);
        if (L == 0)
            k_gemm<false, _Float16><<<dim3(157, 8), 256, 0, stream>>>(gat16, ss, WlWr1t, blr1, xlxr16, NN, 512);
        else
            k_gemm<true, float><<<dim3(157, 1), 256, 0, stream>>>(gat16, ss, mlpWt, mlp_b, mlo, NN, 64);
    }
    k_pool2<<<BB, 256, 0, stream>>>(mlo, batch, pooledDiv);
    k_final<<<1, 320, 0, stream>>>(pooledDiv, out_W, out_b, out);
}

// Round 8
// 464.507 us; speedup vs baseline: 1.0035x; 1.0035x over previous
//
#include <hip/hip_runtime.h>

#define NN 20000
#define EE 320000
#define BB 64

typedef _Float16 half8 __attribute__((ext_vector_type(8)));
typedef float floatx4 __attribute__((ext_vector_type(4)));

// ---------------- prep: weight folding ----------------
__global__ void k_prep_edgeW(const float* __restrict__ edge_W, const float* __restrict__ edge_b,
                             const float* __restrict__ We0, const float* __restrict__ We1,
                             _Float16* __restrict__ Wpt0, _Float16* __restrict__ Wpt1) {
    __shared__ float row[256];
    int k = blockIdx.x, layer = blockIdx.y, j = threadIdx.x;
    row[j] = (k < 63) ? edge_W[k*256 + j] : edge_b[j];
    __syncthreads();
    const float* We = layer ? We1 : We0;
    float acc = 0.f;
    for (int t = 0; t < 256; ++t) acc += row[t] * We[t*256 + j];
    (layer ? Wpt1 : Wpt0)[j*64 + k] = (_Float16)acc;   // transposed [col][k] fp16
}

__global__ void k_prep_acat(const float* __restrict__ node_W, const float* __restrict__ node_b,
                            const float* __restrict__ Wl0, const float* __restrict__ bl0,
                            const float* __restrict__ Wr0, const float* __restrict__ br0,
                            float* __restrict__ Acat) {
    __shared__ float row[256];
    int k = blockIdx.x, j = threadIdx.x;
    if (j < 256) row[j] = (k < 5) ? node_W[k*256 + j] : node_b[j];
    __syncthreads();
    int jj = j & 255;
    const float* W = (j < 256) ? Wl0 : Wr0;
    float acc = 0.f;
    for (int t = 0; t < 256; ++t) acc += row[t] * W[t*256 + jj];
    if (k == 5) acc += (j < 256) ? bl0[jj] : br0[jj];
    Acat[k*512 + j] = acc;
}

__global__ void k_prep_t16(const float* __restrict__ Wl1, const float* __restrict__ bl1,
                           const float* __restrict__ Wr1, const float* __restrict__ br1,
                           const float* __restrict__ mlp_W,
                           _Float16* __restrict__ WlWr1t, float* __restrict__ blr1,
                           _Float16* __restrict__ mlpWt) {
    int n = blockIdx.x, k = threadIdx.x;
    if (n < 512) {
        float v = (n < 256) ? Wl1[k*256 + n] : Wr1[k*256 + (n - 256)];
        WlWr1t[n*256 + k] = (_Float16)v;
        if (k == 0) blr1[n] = (n < 256) ? bl1[n] : br1[n - 256];
    } else {
        int nn = n - 512;
        mlpWt[nn*256 + k] = (_Float16)mlp_W[k*64 + nn];
    }
}

// ---------------- CSR by dst ----------------
__global__ void k_hist(const int* __restrict__ ei, int* __restrict__ counts) {
    int e = blockIdx.x*256 + threadIdx.x;
    if (e < EE) atomicAdd(&counts[ei[EE + e]], 1);
}

__global__ __launch_bounds__(1024) void k_scan(const int* __restrict__ counts,
                                               int* __restrict__ row_ptr, int* __restrict__ cursor) {
    __shared__ int part[1024];
    int t = threadIdx.x;
    const int per = (NN + 1023) / 1024;
    int b0 = t*per, b1 = min(b0 + per, NN);
    int s = 0;
    for (int i = b0; i < b1; ++i) s += counts[i];
    part[t] = s; __syncthreads();
    for (int d = 1; d < 1024; d <<= 1) {
        int v = (t >= d) ? part[t-d] : 0;
        __syncthreads();
        part[t] += v;
        __syncthreads();
    }
    int run = (t == 0) ? 0 : part[t-1];
    for (int i = b0; i < b1; ++i) { row_ptr[i] = run; cursor[i] = run; run += counts[i]; }
    if (t == 0) row_ptr[NN] = EE;
}

__global__ void k_scatter(const int* __restrict__ ei, int* __restrict__ cursor,
                          int* __restrict__ pos, int* __restrict__ csr_src) {
    int e = blockIdx.x*256 + threadIdx.x;
    if (e < EE) {
        int d = ei[EE + e];
        int p = atomicAdd(&cursor[d], 1);
        pos[e] = p;
        csr_src[p] = ei[e];
    }
}

// permute attr into CSR order, fp32->fp16, 64-wide with bias lane (k=63 -> 1.0)
__global__ void k_permattr(const float* __restrict__ attr, const int* __restrict__ pos,
                           _Float16* __restrict__ attr16) {
    int tid = threadIdx.x;
    int w = tid >> 6, lane = tid & 63;
    int e = blockIdx.x*4 + w;
    if (e >= EE) return;
    float v = (lane < 63) ? attr[(size_t)e*63 + lane] : 1.0f;
    attr16[(size_t)pos[e]*64 + lane] = (_Float16)v;
}

// ---------------- layer 0 xl/xr via folded K=5 (fp16 out) ----------------
__global__ void k_xlxr0(const float* __restrict__ x, const float* __restrict__ Acat,
                        _Float16* __restrict__ xlxr16) {
    int n = blockIdx.x, j = threadIdx.x;
    float a0 = Acat[5*512 + j], a1 = Acat[5*512 + 256 + j];
#pragma unroll
    for (int k = 0; k < 5; ++k) {
        float xv = x[n*5 + k];
        a0 += xv * Acat[k*512 + j];
        a1 += xv * Acat[k*512 + 256 + j];
    }
    xlxr16[(size_t)n*512 + j] = (_Float16)a0;
    xlxr16[(size_t)n*512 + 256 + j] = (_Float16)a1;
}

// ---------------- fused GATv2 layer: depth-2 pipelined, barrier-free ----------------
// 4 waves/block; wave w = head w. Single wave-private LDS buffer (write->read same iter).
// Loads for tile i issued during iteration i-2 (2-tile latency window).
#define NPB 4

#define LOADT(Q) { \
    int er = tl + srow; if (er >= el) er = el - 1; \
    const _Float16* sp = &xlxr16[(size_t)csrc[er]*512 + wave*64 + scol]; \
    rx0[Q] = *(const half8*)&sp[0]; \
    rx1[Q] = *(const half8*)&sp[8]; \
    int arow = tl + l15; if (arow >= el) arow = el - 1; \
    const _Float16* ap = &attr16[(size_t)arow*64]; \
    ra0[Q] = *(const half8*)&ap[l4*8]; \
    ra1[Q] = *(const half8*)&ap[32 + l4*8]; \
    rxr[Q] = (float)xlxr16[(size_t)nl*512 + 256 + wave*64 + lane]; \
}

#define FUSED_BODY(CUR) { \
    int nt = ec - tc; if (nt > 16) nt = 16; \
    /* M: MFMA on attr fragments (consumes ra[CUR]) */ \
    floatx4 acc[4]; \
    _Pragma("unroll") \
    for (int ct = 0; ct < 4; ++ct) { \
        floatx4 z = {}; \
        acc[ct] = __builtin_amdgcn_mfma_f32_16x16x32_f16(ra0[CUR], bf[ct][0], z, 0, 0, 0); \
        acc[ct] = __builtin_amdgcn_mfma_f32_16x16x32_f16(ra1[CUR], bf[ct][1], acc[ct], 0, 0, 0); \
    } \
    /* W: stage xl tile to LDS (waits tile-i loads; tile i+1 loads stay in flight) */ \
    *(half8*)&xls[wave][srow][scol]     = rx0[CUR]; \
    *(half8*)&xls[wave][srow][scol + 8] = rx1[CUR]; \
    /* xr fragment via shuffle (consumes rxr[CUR]) */ \
    float xrf[4]; \
    _Pragma("unroll") \
    for (int ct = 0; ct < 4; ++ct) xrf[ct] = __shfl(rxr[CUR], ct*16 + l15); \
    /* L: issue loads for tile i+2 into set CUR */ \
    if (haveL) { LOADT(CUR); haveL = advL(); } \
    /* C: alpha combine + online softmax + accumulate */ \
    float p[4]; \
    _Pragma("unroll") \
    for (int r = 0; r < 4; ++r) { \
        int eidx = l4*4 + r; \
        float pv = 0.f; \
        _Pragma("unroll") \
        for (int ct = 0; ct < 4; ++ct) { \
            float m = acc[ct][r] + (float)xls[wave][eidx][ct*16 + l15] + xrf[ct]; \
            float lr = (m > 0.f) ? m : 0.2f*m; \
            pv += lr * attv[ct]; \
        } \
        pv += __shfl_xor(pv, 1); \
        pv += __shfl_xor(pv, 2); \
        pv += __shfl_xor(pv, 4); \
        pv += __shfl_xor(pv, 8); \
        p[r] = (eidx < nt) ? pv : -3.0e38f; \
    } \
    float aall[16]; \
    _Pragma("unroll") \
    for (int k = 0; k < 16; ++k) aall[k] = __shfl(p[k & 3], (k >> 2) << 4); \
    float mt = aall[0]; \
    _Pragma("unroll") \
    for (int k = 1; k < 16; ++k) mt = fmaxf(mt, aall[k]); \
    float mnew = fmaxf(m_run, mt); \
    float scale = __expf(m_run - mnew); \
    out_acc *= scale; l_run *= scale; \
    _Pragma("unroll") \
    for (int k = 0; k < 16; ++k) { \
        float wk = __expf(aall[k] - mnew); \
        l_run += wk; \
        out_acc += wk * (float)xls[wave][k][lane]; \
    } \
    m_run = mnew; \
    if (tc + 16 >= ec) { \
        gat16[(size_t)nc*256 + wave*64 + lane] = (_Float16)(out_acc / l_run); \
        m_run = -3.0e38f; l_run = 0.f; out_acc = 0.f; \
    } \
}

__global__ __launch_bounds__(256) void k_fused(const _Float16* __restrict__ attr16,
        const int* __restrict__ csrc, const int* __restrict__ row_ptr,
        const _Float16* __restrict__ Wpt, const float* __restrict__ att,
        const _Float16* __restrict__ xlxr16, _Float16* __restrict__ gat16) {
    int tid = threadIdx.x;
    int wave = tid >> 6, lane = tid & 63;
    int l15 = lane & 15, l4 = lane >> 4;
    int srow = lane >> 2, scol = (lane & 3) * 16;

    __shared__ __align__(16) _Float16 xls[4][16][72];   // wave-private single buffer

    // block-invariant: B fragments (Wpt) + att for this wave's head
    half8 bf[4][2];
    float attv[4];
#pragma unroll
    for (int ct = 0; ct < 4; ++ct) {
        int c = wave*64 + ct*16 + l15;
        attv[ct] = att[c];
        bf[ct][0] = *(const half8*)&Wpt[(size_t)c*64 + l4*8];
        bf[ct][1] = *(const half8*)&Wpt[(size_t)c*64 + 32 + l4*8];
    }

    int n0 = blockIdx.x*NPB;
    int nEnd = n0 + NPB; if (nEnd > NN) nEnd = NN;

    // zero-fill empty nodes; find first nonempty
    int nc = -1, tc = 0, ec = 0;
    for (int m = n0; m < nEnd; ++m) {
        int s = row_ptr[m], e = row_ptr[m+1];
        if (e <= s) gat16[(size_t)m*256 + wave*64 + lane] = (_Float16)0.f;
        else if (nc < 0) { nc = m; tc = s; ec = e; }
    }
    if (nc < 0) return;

    // loads iterator (starts at tile 0)
    int nl = nc, tl = tc, el = ec;
    auto advIt = [&](int& n, int& t, int& e) -> bool {
        t += 16;
        if (t < e) return true;
        for (;;) {
            ++n;
            if (n >= nEnd) return false;
            int s = row_ptr[n]; e = row_ptr[n+1];
            if (e > s) { t = s; return true; }
        }
    };
    auto advL = [&]() -> bool { return advIt(nl, tl, el); };

    half8 rx0[2], rx1[2], ra0[2], ra1[2];
    float rxr[2];

    // prologue: tiles 0 and 1
    LOADT(0);
    bool haveL = advL();
    if (haveL) { LOADT(1); haveL = advL(); }

    float m_run = -3.0e38f, l_run = 0.f, out_acc = 0.f;
    for (;;) {
        FUSED_BODY(0);
        if (!advIt(nc, tc, ec)) break;
        FUSED_BODY(1);
        if (!advIt(nc, tc, ec)) break;
    }
}

// ---------------- batchnorm (stats from fp16, apply fused into GEMM) ----------------
__global__ void k_bn_stats(const _Float16* __restrict__ X, float* __restrict__ stats) {
    int j = threadIdx.x;
    int shard = blockIdx.x & 15;
    float s = 0.f, q = 0.f;
    for (int r = blockIdx.x; r < NN; r += gridDim.x) {
        float v = (float)X[(size_t)r*256 + j];
        s += v; q += v*v;
    }
    atomicAdd(&stats[shard*512 + j], s);
    atomicAdd(&stats[shard*512 + 256 + j], q);
}

__global__ void k_bn_final(const float* __restrict__ stats, const float* __restrict__ gamma,
                           const float* __restrict__ beta, float* __restrict__ ss) {
    int j = threadIdx.x;
    float s = 0.f, q = 0.f;
#pragma unroll
    for (int sh = 0; sh < 16; ++sh) {
        s += stats[sh*512 + j];
        q += stats[sh*512 + 256 + j];
    }
    float mean = s * (1.0f/NN);
    float var  = q * (1.0f/NN) - mean*mean;
    float sc = rsqrtf(var + 1e-5f) * gamma[j];
    ss[j] = sc;
    ss[256 + j] = beta[j] - mean*sc;
}

// ---------------- fp16 MFMA GEMM with fused BN+ReLU on A ----------------
template<bool RELU, typename OT>
__global__ __launch_bounds__(256) void k_gemm(const _Float16* __restrict__ A,
                       const float* __restrict__ ssv,
                       const _Float16* __restrict__ Bt,
                       const float* __restrict__ bias, OT* __restrict__ C,
                       int M, int ldc) {
    __shared__ __align__(16) _Float16 As[128][72];
    __shared__ __align__(16) _Float16 Bs[64][72];
    int tid = threadIdx.x;
    int wave = tid >> 6, lane = tid & 63;
    int l15 = lane & 15, l4 = lane >> 4;
    int row0 = blockIdx.x*128, n0 = blockIdx.y*64;
    floatx4 acc[2][4] = {};
    for (int k0 = 0; k0 < 256; k0 += 64) {
#pragma unroll
        for (int q = 0; q < 4; ++q) {
            int c = tid + q*256;
            int r = c >> 3, kc = (c & 7)*8;
            int gr = row0 + r; if (gr >= M) gr = M - 1;
            half8 g = *(const half8*)&A[(size_t)gr*256 + k0 + kc];
            _Float16 tmp[8];
#pragma unroll
            for (int i = 0; i < 8; ++i) {
                int colk = k0 + kc + i;
                float v = (float)g[i]*ssv[colk] + ssv[256 + colk];
                tmp[i] = (_Float16)fmaxf(v, 0.f);
            }
            *(half8*)&As[r][kc] = *(half8*)tmp;
        }
#pragma unroll
        for (int q = 0; q < 2; ++q) {
            int c = tid + q*256;
            int r = c >> 3, kc = (c & 7)*8;
            *(half8*)&Bs[r][kc] = *(const half8*)&Bt[(size_t)(n0 + r)*256 + k0 + kc];
        }
        __syncthreads();
#pragma unroll
        for (int ks = 0; ks < 64; ks += 32) {
            half8 a0 = *(const half8*)&As[wave*32 + l15][ks + l4*8];
            half8 a1 = *(const half8*)&As[wave*32 + 16 + l15][ks + l4*8];
#pragma unroll
            for (int nb = 0; nb < 4; ++nb) {
                half8 b = *(const half8*)&Bs[nb*16 + l15][ks + l4*8];
                acc[0][nb] = __builtin_amdgcn_mfma_f32_16x16x32_f16(a0, b, acc[0][nb], 0, 0, 0);
                acc[1][nb] = __builtin_amdgcn_mfma_f32_16x16x32_f16(a1, b, acc[1][nb], 0, 0, 0);
            }
        }
        __syncthreads();
    }
#pragma unroll
    for (int m = 0; m < 2; ++m)
#pragma unroll
    for (int nb = 0; nb < 4; ++nb) {
        int col = n0 + nb*16 + l15;
        float bv = bias[col];
#pragma unroll
        for (int r = 0; r < 4; ++r) {
            int grow = row0 + wave*32 + m*16 + l4*4 + r;
            if (grow < M) {
                float v = acc[m][nb][r] + bv;
                if (RELU) v = fmaxf(v, 0.f);
                C[(size_t)grow*ldc + col] = (OT)v;
            }
        }
    }
}

// ---------------- pooling (batch sorted -> contiguous ranges, no atomics) ----------------
__global__ void k_pool2(const float* __restrict__ mo, const int* __restrict__ batch,
                        float* __restrict__ pooledDiv) {
    int b = blockIdx.x;
    int j = threadIdx.x & 63, rg = threadIdx.x >> 6;
    int lo = 0, hi = NN;
    while (lo < hi) { int mid = (lo + hi) >> 1; if (batch[mid] < b) lo = mid + 1; else hi = mid; }
    int s = lo;
    lo = 0; hi = NN;
    while (lo < hi) { int mid = (lo + hi) >> 1; if (batch[mid] < b + 1) lo = mid + 1; else hi = mid; }
    int e = lo;
    float acc = 0.f;
    for (int r = s + rg; r < e; r += 4) acc += mo[(size_t)r*64 + j];
    __shared__ float red[256];
    red[threadIdx.x] = acc;
    __syncthreads();
    if (rg == 0) {
        float v = red[j] + red[64 + j] + red[128 + j] + red[192 + j];
        pooledDiv[b*64 + j] = v / fmaxf((float)(e - s), 1.f);
    }
}

__global__ void k_final(const float* __restrict__ pooledDiv,
                        const float* __restrict__ outW, const float* __restrict__ outb,
                        float* __restrict__ out) {
    int t = threadIdx.x;
    if (t >= 320) return;
    int b = t / 5, c = t % 5;
    float acc = outb[c];
    for (int k = 0; k < 64; ++k) acc += pooledDiv[b*64 + k] * outW[k*5 + c];
    out[t] = acc;
}

extern "C" void kernel_launch(void* const* d_in, const int* in_sizes, int n_in,
                              void* d_out, int out_size, void* d_ws, size_t ws_size,
                              hipStream_t stream) {
    const float* x      = (const float*)d_in[0];
    const int*   ei     = (const int*)d_in[1];
    const float* attr   = (const float*)d_in[2];
    const int*   batch  = (const int*)d_in[3];
    const float* node_W = (const float*)d_in[4];
    const float* node_b = (const float*)d_in[5];
    const float* edge_W = (const float*)d_in[6];
    const float* edge_b = (const float*)d_in[7];
    const float* Wl[2]   = {(const float*)d_in[8],  (const float*)d_in[17]};
    const float* bl[2]   = {(const float*)d_in[9],  (const float*)d_in[18]};
    const float* Wr[2]   = {(const float*)d_in[10], (const float*)d_in[19]};
    const float* br[2]   = {(const float*)d_in[11], (const float*)d_in[20]};
    const float* We[2]   = {(const float*)d_in[12], (const float*)d_in[21]};
    const float* att[2]  = {(const float*)d_in[13], (const float*)d_in[22]};
    const float* gamma[2]= {(const float*)d_in[15], (const float*)d_in[24]};
    const float* beta[2] = {(const float*)d_in[16], (const float*)d_in[25]};
    const float* mlp_W = (const float*)d_in[26];
    const float* mlp_b = (const float*)d_in[27];
    const float* out_W = (const float*)d_in[28];
    const float* out_b = (const float*)d_in[29];
    float* out = (float*)d_out;

    char* p = (char*)d_ws;
    size_t off = 0;
    auto carve = [&](size_t bytes) -> void* {
        void* r = p + off;
        off = (off + bytes + 255) & ~(size_t)255;
        return r;
    };
    _Float16* Wpt0   = (_Float16*)carve(256*64*2);
    _Float16* Wpt1   = (_Float16*)carve(256*64*2);
    float*    Acat   = (float*)carve(6*512*4);
    _Float16* WlWr1t = (_Float16*)carve(512*256*2);
    float*    blr1   = (float*)carve(512*4);
    _Float16* mlpWt  = (_Float16*)carve(64*256*2);
    float*    ss     = (float*)carve(512*4);
    _Float16* xlxr16 = (_Float16*)carve((size_t)NN*512*2);
    _Float16* gat16  = (_Float16*)carve((size_t)NN*256*2);
    float*    mlo    = (float*)carve((size_t)NN*64*4);
    _Float16* attr16 = (_Float16*)carve((size_t)EE*64*2);
    int*      row_ptr= (int*)carve((NN+1)*4);
    int*      pos    = (int*)carve((size_t)EE*4);
    int*      csrc   = (int*)carve((size_t)EE*4);
    int*      cursor = (int*)carve(NN*4);
    float*    pooledDiv = (float*)carve(BB*64*4);
    char*     zz     = (char*)carve((NN + 16384)*4);
    int*      counts = (int*)zz;
    float*    stats  = (float*)(zz + (size_t)NN*4);   // 2 layers x 16 shards x 512
    if (off > ws_size) return;  // workspace too small: bail

    hipMemsetAsync(zz, 0, (size_t)(NN + 16384)*4, stream);
    k_prep_edgeW<<<dim3(64,2), 256, 0, stream>>>(edge_W, edge_b, We[0], We[1], Wpt0, Wpt1);
    k_prep_acat<<<6, 512, 0, stream>>>(node_W, node_b, Wl[0], bl[0], Wr[0], br[0], Acat);
    k_prep_t16<<<576, 256, 0, stream>>>(Wl[1], bl[1], Wr[1], br[1], mlp_W, WlWr1t, blr1, mlpWt);
    k_hist<<<(EE+255)/256, 256, 0, stream>>>(ei, counts);
    k_scan<<<1, 1024, 0, stream>>>(counts, row_ptr, cursor);
    k_scatter<<<(EE+255)/256, 256, 0, stream>>>(ei, cursor, pos, csrc);
    k_permattr<<<EE/4, 256, 0, stream>>>(attr, pos, attr16);
    k_xlxr0<<<NN, 256, 0, stream>>>(x, Acat, xlxr16);

    for (int L = 0; L < 2; ++L) {
        k_fused<<<(NN + NPB - 1)/NPB, 256, 0, stream>>>(attr16, csrc, row_ptr,
                 L ? Wpt1 : Wpt0, att[L], xlxr16, gat16);
        k_bn_stats<<<1024, 256, 0, stream>>>(gat16, stats + L*8192);
        k_bn_final<<<1, 256, 0, stream>>>(stats + L*8192, gamma[L], beta[L], ss);
        if (L == 0)
            k_gemm<false, _Float16><<<dim3(157, 8), 256, 0, stream>>>(gat16, ss, WlWr1t, blr1, xlxr16, NN, 512);
        else
            k_gemm<true, float><<<dim3(157, 1), 256, 0, stream>>>(gat16, ss, mlpWt, mlp_b, mlo, NN, 64);
    }
    k_pool2<<<BB, 256, 0, stream>>>(mlo, batch, pooledDiv);
    k_final<<<1, 320, 0, stream>>>(pooledDiv, out_W, out_b, out);
}